// Round 5
// baseline (422.508 us; speedup 1.0000x reference)
//
#include <hip/hip_runtime.h>

// NTM cell forward. f32 in/out, bf16 MFMA for all large GEMMs (tolerance is bf16-grade).
// B=2048 N=256 M=64 U=512 IN=10 SHIFT=1 CLIP=20
// Outputs flat (f32): y_t[B*512] | m_t[B*256*64] | R_t[B*64] | w_read[B*256] | w_write[B*256]
// R5: k_addr retains m0 as PACKED BF16 in registers (32 VGPRs) -> fits 6 blocks/CU
//     (launch_bounds(256,6)); no phase-3 re-read; ipbuf padded (bank-conflict fix).

using u16   = unsigned short;
using bfrag = __attribute__((ext_vector_type(8))) short;   // 8 bf16 (4 VGPRs)
using f4    = __attribute__((ext_vector_type(4))) float;   // MFMA accumulator

__device__ __forceinline__ float bf2f(u16 s){ union{float f;unsigned u;}v; v.u=((unsigned)s)<<16; return v.f; }
__device__ __forceinline__ u16 f2bf(float f){ union{float f;unsigned u;}v; v.f=f; unsigned r=v.u+0x7fffu+((v.u>>16)&1u); return (u16)(r>>16); }
__device__ __forceinline__ void bfpair(unsigned pr, float&a, float&b){ union{float f;unsigned u;}x,y; x.u=pr<<16; y.u=pr&0xffff0000u; a=x.f; b=y.f; }
__device__ __forceinline__ unsigned packbf(float a, float b){ return (unsigned)f2bf(a) | ((unsigned)f2bf(b)<<16); }
__device__ __forceinline__ float sigm(float x){ return 1.f/(1.f+expf(-x)); }
__device__ __forceinline__ float softplus_(float x){ return fmaxf(x,0.f)+log1pf(expf(-fabsf(x))); }

// async global->LDS, 16B per lane; lptr must be wave-uniform (HW adds lane*16)
__device__ __forceinline__ void gld16(const u16* g, u16* l){
    __builtin_amdgcn_global_load_lds((const __attribute__((address_space(1))) unsigned*)g,
                                     (__attribute__((address_space(3))) unsigned*)l, 16, 0, 0);
}

// ======================= fused prep: weight transposes + A-build, one launch =======================
// role 0 (blocks [0,2112)):    Wt_lstm  [n'][k] bf16, lda=1056, GATE-INTERLEAVED rows:
//                              orig col n = gate*512+u  ->  n' = (u>>4)*64 + gate*16 + (u&15)
// role 1 (blocks [2112,2304)): Wt_h [n][k] bf16 (n<384 pad), ldb=512
// role 2 (blocks [2304,2592)): Wt_o [n][k] bf16, ldb=576
// role 3 (blocks [2592,6688)): Abuf = [x | R0@Wprep+bprep | H0 | 0], bf16, lda=1056
__global__ __launch_bounds__(256) void k_prep(const float* __restrict__ Wx, const float* __restrict__ Wh,
                                              const float* __restrict__ Wr, const float* __restrict__ Ww,
                                              const float* __restrict__ Wo,
                                              const float* __restrict__ x, const float* __restrict__ H0,
                                              const float* __restrict__ R0, const float* __restrict__ Wprep,
                                              const float* __restrict__ bprep,
                                              u16* __restrict__ Wt_lstm, u16* __restrict__ Wt_h,
                                              u16* __restrict__ Wt_o, u16* __restrict__ Abuf){
    __shared__ float t[32][33];
    int bx = blockIdx.x;
    int tx = threadIdx.x & 31, ty = threadIdx.x >> 5;
    if(bx < 2112){                       // ---- Wt_lstm transpose + gate interleave ----
        int n0 = (bx & 63)*32, k0 = (bx >> 6)*32;
        #pragma unroll
        for(int r=0;r<4;r++){
            int k = k0 + ty*4 + r, n = n0 + tx;
            float v;
            if(k < 522)       v = Wx[k*2048 + n];
            else if(k < 1034) v = Wh[(k-522)*2048 + n];
            else              v = 0.f;
            t[ty*4+r][tx] = v;
        }
        __syncthreads();
        #pragma unroll
        for(int r=0;r<4;r++){
            int n = n0 + ty*4 + r, k = k0 + tx;
            int u = n & 511, gate = n >> 9;
            int np = ((u>>4)<<6) + (gate<<4) + (u&15);   // gate-interleaved row
            Wt_lstm[np*1056 + k] = f2bf(t[tx][ty*4+r]);
        }
    } else if(bx < 2304){                // ---- Wt_h transpose ----
        int idx = bx - 2112;
        int n0 = (idx % 12)*32, k0 = (idx / 12)*32;
        #pragma unroll
        for(int r=0;r<4;r++){
            int k = k0 + ty*4 + r, n = n0 + tx;
            float v;
            if(n < 70)        v = Wr[k*70 + n];
            else if(n < 268)  v = Ww[k*198 + (n-70)];
            else              v = 0.f;
            t[ty*4+r][tx] = v;
        }
        __syncthreads();
        #pragma unroll
        for(int r=0;r<4;r++){
            int n = n0 + ty*4 + r, k = k0 + tx;
            Wt_h[n*512 + k] = f2bf(t[tx][ty*4+r]);
        }
    } else if(bx < 2592){                // ---- Wt_o transpose ----
        int idx = bx - 2304;
        int n0 = (idx % 16)*32, k0 = (idx / 16)*32;
        #pragma unroll
        for(int r=0;r<4;r++){
            int k = k0 + ty*4 + r, n = n0 + tx;
            t[ty*4+r][tx] = Wo[k*512 + n];
        }
        __syncthreads();
        #pragma unroll
        for(int r=0;r<4;r++){
            int n = n0 + ty*4 + r, k = k0 + tx;
            Wt_o[n*576 + k] = f2bf(t[tx][ty*4+r]);
        }
    } else {                             // ---- A-build ----
        int flat = (bx - 2592)*256 + threadIdx.x;   // B*512
        int b = flat >> 9, u = flat & 511;
        u16* Ab = Abuf + (size_t)b*1056;
        float acc = bprep[u];
        const float* r = R0 + b*64;
        #pragma unroll 8
        for(int m=0;m<64;m++) acc += r[m] * Wprep[m*512+u];
        Ab[10+u] = f2bf(acc);
        Ab[522+u] = f2bf(H0[b*512+u]);
        if(u<10) Ab[u] = f2bf(x[b*10+u]);
        if(u<22) Ab[1034+u] = 0;                   // zero K-pad 1034..1055
    }
}

// ======================= MFMA GEMM core: 128x128 C tile, BK=32 =======================
// A: M x K row-major bf16 (lda), Bt: N x K row-major bf16 (ldb). 256 threads = 4 waves,
// wave (wr,wc) owns 64x64 = 4x4 of 16x16x32 MFMAs. m97 2-barrier structure.
__device__ __forceinline__ void gemm128(const u16* __restrict__ A, int lda,
                                        const u16* __restrict__ Bt, int ldb,
                                        int bm, int bn, int kiters,
                                        u16* Al, u16* Bl, f4 acc[4][4]){
    int tid = threadIdx.x, w = tid>>6, lane = tid&63, quad = lane>>4, l16 = lane&15;
    int wr = w>>1, wc = w&1;
    f4 z4 = {0.f,0.f,0.f,0.f};
    #pragma unroll
    for(int i=0;i<4;i++)
        #pragma unroll
        for(int j=0;j<4;j++) acc[i][j] = z4;
    int rA0 = tid>>2, kc = tid&3;
    int rA1 = rA0 + 64;
    const u16* ga0 = A  + (size_t)(bm+rA0)*lda + kc*8;
    const u16* ga1 = A  + (size_t)(bm+rA1)*lda + kc*8;
    const u16* gb0 = Bt + (size_t)(bn+rA0)*ldb + kc*8;
    const u16* gb1 = Bt + (size_t)(bn+rA1)*ldb + kc*8;
    u16* lA0 = Al + (w*64)*8;
    u16* lA1 = Al + (256 + w*64)*8;
    u16* lB0 = Bl + (w*64)*8;
    u16* lB1 = Bl + (256 + w*64)*8;
    for(int kt=0; kt<kiters; kt++){
        __syncthreads();
        gld16(ga0, lA0); gld16(ga1, lA1);
        gld16(gb0, lB0); gld16(gb1, lB1);
        ga0 += 32; ga1 += 32; gb0 += 32; gb1 += 32;
        __syncthreads();
        bfrag af[4], bf[4];
        #pragma unroll
        for(int i=0;i<4;i++) af[i] = *(const bfrag*)&Al[(wr*64 + i*16 + l16)*32 + quad*8];
        #pragma unroll
        for(int j=0;j<4;j++) bf[j] = *(const bfrag*)&Bl[(wc*64 + j*16 + l16)*32 + quad*8];
        #pragma unroll
        for(int i=0;i<4;i++)
            #pragma unroll
            for(int j=0;j<4;j++)
                acc[i][j] = __builtin_amdgcn_mfma_f32_16x16x32_bf16(af[i], bf[j], acc[i][j], 0, 0, 0);
    }
}
// C/D mapping (m89-verified): col = lane&15, row = quad*4 + reg.

// ------------- GEMM 1 + fused LSTM gates: A@Wt_lstm^T with gate-interleaved cols -------------
__global__ __launch_bounds__(256) void k_gemm_lstm(const u16* __restrict__ A, const u16* __restrict__ Wt,
                                                   const float* __restrict__ C0, const float* __restrict__ bl,
                                                   u16* __restrict__ A2){
    __shared__ u16 Al[128*32], Bl[128*32];
    f4 acc[4][4];
    int bm = blockIdx.x*128, bn = blockIdx.y*128;
    gemm128(A, 1056, Wt, 1056, bm, bn, 33, Al, Bl, acc);
    int lane = threadIdx.x&63, quad = lane>>4, l16 = lane&15, w = threadIdx.x>>6;
    int wr = w>>1, wc = w&1;
    int u = (((bn + wc*64)>>6)<<4) + l16;
    float bi = bl[u], bff = bl[512+u], bg = bl[1024+u], bo_ = bl[1536+u];
    #pragma unroll
    for(int i=0;i<4;i++){
        #pragma unroll
        for(int r=0;r<4;r++){
            int b = bm + wr*64 + i*16 + quad*4 + r;
            float zi = acc[i][0][r] + bi;
            float zf = acc[i][1][r] + bff;
            float zg = acc[i][2][r] + bg;
            float zo = acc[i][3][r] + bo_;
            float c  = sigm(zf)*C0[b*512+u] + sigm(zi)*tanhf(zg);
            float hv = sigm(zo)*tanhf(c);
            hv = fminf(fmaxf(hv,-20.f),20.f);
            A2[(size_t)b*576 + u] = f2bf(hv);
        }
    }
}

// ------------- GEMM 2: [rout|wout] = h @ Wt_h^T  (2048 x 268(pad 384), K=512) -------------
__global__ __launch_bounds__(256) void k_gemm_heads(const u16* __restrict__ A2, const u16* __restrict__ Wt,
                                                    const float* __restrict__ br, const float* __restrict__ bw,
                                                    float* __restrict__ rout, float* __restrict__ wout){
    __shared__ u16 Al[128*32], Bl[128*32];
    f4 acc[4][4];
    int bm = blockIdx.x*128, bn = blockIdx.y*128;
    gemm128(A2, 576, Wt, 512, bm, bn, 16, Al, Bl, acc);
    int lane = threadIdx.x&63, quad = lane>>4, l16 = lane&15, w = threadIdx.x>>6;
    int wr = w>>1, wc = w&1;
    #pragma unroll
    for(int i=0;i<4;i++){
        #pragma unroll
        for(int j=0;j<4;j++){
            int col = bn + wc*64 + j*16 + l16;
            if(col >= 268) continue;
            #pragma unroll
            for(int r=0;r<4;r++){
                int row = bm + wr*64 + i*16 + quad*4 + r;
                float v = acc[i][j][r];
                if(col < 70) rout[(size_t)row*70 + col]        = v + br[col];
                else         wout[(size_t)row*198 + (col-70)]  = v + bw[col-70];
            }
        }
    }
}

// ------------- GEMM 3: y = clip([h|R_t] @ Wt_o^T + bo)  (2048 x 512, K=576) -------------
__global__ __launch_bounds__(256) void k_gemm_out(const u16* __restrict__ A2, const u16* __restrict__ Wt,
                                                  const float* __restrict__ bo, float* __restrict__ y){
    __shared__ u16 Al[128*32], Bl[128*32];
    f4 acc[4][4];
    int bm = blockIdx.x*128, bn = blockIdx.y*128;
    gemm128(A2, 576, Wt, 576, bm, bn, 18, Al, Bl, acc);
    int lane = threadIdx.x&63, quad = lane>>4, l16 = lane&15, w = threadIdx.x>>6;
    int wr = w>>1, wc = w&1;
    #pragma unroll
    for(int i=0;i<4;i++){
        #pragma unroll
        for(int j=0;j<4;j++){
            int col = bn + wc*64 + j*16 + l16;
            float bias = bo[col];
            #pragma unroll
            for(int r=0;r<4;r++){
                int row = bm + wr*64 + i*16 + quad*4 + r;
                float v = acc[i][j][r] + bias;
                v = fminf(fmaxf(v,-20.f),20.f);
                y[(size_t)row*512 + col] = v;
            }
        }
    }
}

// ------------- K4: per-b fused addressing (both heads) + R_t + m_t -------------
// R5: m0 read ONCE, retained as PACKED BF16 in 32 VGPRs/thread (bf16 rounding of m0 is
// within tolerance — r1 did the same via LDS). launch_bounds(256,6) -> 6 blocks/CU.
// ipbuf padded (idx = n + (n>>4)) to spread the redistribute across 16 banks.
__global__ __launch_bounds__(256, 6) void k_addr(const float* __restrict__ m0, const float* __restrict__ A0,
                                              const float* __restrict__ rout, const float* __restrict__ wout,
                                              u16* __restrict__ A2,
                                              float* __restrict__ out_mt, float* __restrict__ out_rt,
                                              float* __restrict__ out_wr, float* __restrict__ out_ww){
    __shared__ __align__(16) float kk_s[2][64];   // tanh(k), both heads
    __shared__ float knorm_s[2];
    __shared__ float sc[2][6];                    // beta-sp, g, s0,s1,s2, gamma-sp
    __shared__ float ipbuf[3][272];               // padded: slot(n) = n + (n>>4)
    __shared__ float wgrr[512];                   // phase1: wg_s[2][256]; phase2: rred[8][64]
    __shared__ float wsel[2][256];
    __shared__ __align__(16) float dv[64], avv[64];
    __shared__ float wpart[4][6];                 // per-wave reduce partials
    int tid = threadIdx.x, b = blockIdx.x;
    int lane = tid & 63, w = tid >> 6;
    int g = tid >> 4, c = tid & 15, mc = c*4;

    // early independent global loads
    float a0r = A0[b*256 + tid];
    float a1r = A0[524288 + b*256 + tid];

    // ---- m0 -> registers, packed bf16 (32 VGPRs), single HBM read ----
    unsigned vp0[16], vp1[16];
    const float* mb = m0 + (size_t)b*16384;
    #pragma unroll
    for(int i=0;i<16;i++){
        float4 v = *(const float4*)(mb + i*1024 + tid*4);
        vp0[i] = packbf(v.x, v.y);
        vp1[i] = packbf(v.z, v.w);
    }
    // (vp0[i],vp1[i]) = m0[b][i*16+g][mc..mc+3] (bf16-rounded)

    // ---- head scalars, split across waves ----
    if(tid < 128){
        int hh = tid >> 6, m = lane;
        float kv = tanhf(hh ? wout[b*198 + m] : rout[b*70 + m]);
        kk_s[hh][m] = kv;
        float s2 = kv*kv;
        #pragma unroll
        for(int o=32;o>0;o>>=1) s2 += __shfl_xor(s2, o, 64);
        if(m == 0) knorm_s[hh] = sqrtf(s2);
    } else if(tid < 192){
        int hh = tid - 128;
        if(hh < 2){
            const float* hd = hh ? (wout + b*198) : (rout + b*70);
            sc[hh][0] = softplus_(hd[64]);
            sc[hh][1] = sigm(hd[65]);
            float e0=hd[66], e1=hd[67], e2=hd[68];
            float mx = fmaxf(e0, fmaxf(e1, e2));
            float x0=expf(e0-mx), x1=expf(e1-mx), x2=expf(e2-mx);
            float ssum = x0+x1+x2;
            sc[hh][2]=x0/ssum; sc[hh][3]=x1/ssum; sc[hh][4]=x2/ssum;
            sc[hh][5] = softplus_(hd[69]);
        }
    } else {
        int m = tid - 192;
        dv[m]  = sigm(wout[b*198 + 70 + m]);
        avv[m] = tanhf(wout[b*198 + 134 + m]);
    }
    __syncthreads();   // (1) kk_s/sc/dv/avv visible

    // ---- dual-head ip + ssq per row, 16-lane-group butterfly, redistribute ----
    {
        float4 ka = *(const float4*)&kk_s[0][mc];
        float4 kb = *(const float4*)&kk_s[1][mc];
        float rip0=0.f, rip1=0.f, rssq=0.f;
        #pragma unroll
        for(int i=0;i<16;i++){
            float v0,v1,v2,v3;
            bfpair(vp0[i], v0, v1);
            bfpair(vp1[i], v2, v3);
            float p0 = v0*ka.x + v1*ka.y + v2*ka.z + v3*ka.w;
            float p1 = v0*kb.x + v1*kb.y + v2*kb.z + v3*kb.w;
            float ps = v0*v0 + v1*v1 + v2*v2 + v3*v3;
            #pragma unroll
            for(int o=1;o<16;o<<=1){
                p0 += __shfl_xor(p0, o);
                p1 += __shfl_xor(p1, o);
                ps += __shfl_xor(ps, o);
            }
            if(c == i){ rip0 = p0; rip1 = p1; rssq = ps; }
        }
        int slot = c*17 + g;       // padded slot for row n = c*16+g
        ipbuf[0][slot] = rip0;
        ipbuf[1][slot] = rip1;
        ipbuf[2][slot] = rssq;
    }
    __syncthreads();   // (2) ipbuf visible
    int rslot = tid + (tid>>4);
    float ip0 = ipbuf[0][rslot], ip1 = ipbuf[1][rslot], ssq = ipbuf[2][rslot];

    float mn = sqrtf(ssq);
    float K0 = ip0 / (knorm_s[0]*mn + 1e-8f);
    float K1 = ip1 / (knorm_s[1]*mn + 1e-8f);
    float e0 = sc[0][0]*K0, e1 = sc[1][0]*K1;

    // ---- softmax max (both heads): wave shuffle + 4-slot combine ----
    float mx0 = e0, mx1 = e1;
    #pragma unroll
    for(int o=32;o>0;o>>=1){ mx0 = fmaxf(mx0, __shfl_xor(mx0,o,64)); mx1 = fmaxf(mx1, __shfl_xor(mx1,o,64)); }
    if(lane == 0){ wpart[w][0] = mx0; wpart[w][1] = mx1; }
    __syncthreads();   // (3)
    mx0 = fmaxf(fmaxf(wpart[0][0],wpart[1][0]), fmaxf(wpart[2][0],wpart[3][0]));
    mx1 = fmaxf(fmaxf(wpart[0][1],wpart[1][1]), fmaxf(wpart[2][1],wpart[3][1]));
    float p0 = expf(e0-mx0), p1 = expf(e1-mx1);
    float s0 = p0, s1 = p1;
    #pragma unroll
    for(int o=32;o>0;o>>=1){ s0 += __shfl_xor(s0,o,64); s1 += __shfl_xor(s1,o,64); }
    if(lane == 0){ wpart[w][2] = s0; wpart[w][3] = s1; }
    __syncthreads();   // (4)
    s0 = wpart[0][2]+wpart[1][2]+wpart[2][2]+wpart[3][2];
    s1 = wpart[0][3]+wpart[1][3]+wpart[2][3]+wpart[3][3];
    float wc0 = p0/s0, wc1 = p1/s1;

    // ---- gate + shift-conv + sharpen (both heads) ----
    float g0 = sc[0][1], g1 = sc[1][1];
    float wg0 = g0*wc0 + (1.f-g0)*a0r;
    float wg1 = g1*wc1 + (1.f-g1)*a1r;
    wgrr[tid] = wg0; wgrr[256+tid] = wg1;
    __syncthreads();   // (5)
    int nm1 = (tid+255)&255, np1 = (tid+1)&255;
    float conv0 = sc[0][2]*wg0 + sc[0][3]*wgrr[nm1]     + sc[0][4]*wgrr[np1];
    float conv1 = sc[1][2]*wg1 + sc[1][3]*wgrr[256+nm1] + sc[1][4]*wgrr[256+np1];
    conv0 = fmaxf(conv0, 1e-35f);  conv1 = fmaxf(conv1, 1e-35f);
    float wsh0 = expf(sc[0][5]*logf(conv0));
    float wsh1 = expf(sc[1][5]*logf(conv1));
    float t0 = wsh0, t1 = wsh1;
    #pragma unroll
    for(int o=32;o>0;o>>=1){ t0 += __shfl_xor(t0,o,64); t1 += __shfl_xor(t1,o,64); }
    if(lane == 0){ wpart[w][4] = t0; wpart[w][5] = t1; }
    __syncthreads();   // (6)
    t0 = wpart[0][4]+wpart[1][4]+wpart[2][4]+wpart[3][4];
    t1 = wpart[0][5]+wpart[1][5]+wpart[2][5]+wpart[3][5];
    float w0 = wsh0/t0, w1 = wsh1/t1;
    wsel[0][tid] = w0; wsel[1][tid] = w1;
    out_wr[b*256 + tid] = w0;
    out_ww[b*256 + tid] = w1;
    __syncthreads();   // (7) wsel visible; wgrr dead -> reusable as rred

    // ---- m_t from retained packed registers + fused R_t partials ----
    float r0=0.f, r1=0.f, r2=0.f, r3=0.f;
    {
        float d0=dv[mc], d1=dv[mc+1], d2=dv[mc+2], d3=dv[mc+3];
        float A0v=avv[mc], A1v=avv[mc+1], A2v=avv[mc+2], A3v=avv[mc+3];
        float* outb = out_mt + (size_t)b*16384;
        #pragma unroll
        for(int i=0;i<16;i++){
            int n = i*16 + g;
            float wwv = wsel[1][n], wrv = wsel[0][n];   // 16-lane broadcast
            float v0,v1,v2,v3;
            bfpair(vp0[i], v0, v1);
            bfpair(vp1[i], v2, v3);
            float4 o;
            o.x = v0*(1.f - wwv*d0) + wwv*A0v;
            o.y = v1*(1.f - wwv*d1) + wwv*A1v;
            o.z = v2*(1.f - wwv*d2) + wwv*A2v;
            o.w = v3*(1.f - wwv*d3) + wwv*A3v;
            *(float4*)(outb + i*1024 + tid*4) = o;
            r0 += wrv*v0; r1 += wrv*v1; r2 += wrv*v2; r3 += wrv*v3;
        }
    }
    // ---- R_t reduce: 16 n-groups -> 8 (register add) -> 64 (tree over rred) ----
    {
        float* rred = wgrr;                 // [8][64]
        if(g >= 8){
            rred[(g-8)*64 + mc]   = r0;
            rred[(g-8)*64 + mc+1] = r1;
            rred[(g-8)*64 + mc+2] = r2;
            rred[(g-8)*64 + mc+3] = r3;
        }
        __syncthreads();   // (8)
        if(g < 8){
            rred[g*64 + mc]   += r0;
            rred[g*64 + mc+1] += r1;
            rred[g*64 + mc+2] += r2;
            rred[g*64 + mc+3] += r3;
        }
        __syncthreads();   // (9)
        if(tid < 64){
            float rt = 0.f;
            #pragma unroll
            for(int g2=0; g2<8; g2++) rt += rred[g2*64 + tid];
            out_rt[b*64 + tid] = rt;
            A2[(size_t)b*576 + 512 + tid] = f2bf(rt);   // feed out-GEMM
        }
    }
}

extern "C" void kernel_launch(void* const* d_in, const int* in_sizes, int n_in,
                              void* d_out, int out_size, void* d_ws, size_t ws_size,
                              hipStream_t stream) {
    const float* x     = (const float*)d_in[0];
    const float* H0    = (const float*)d_in[1];
    const float* C0    = (const float*)d_in[2];
    const float* m0    = (const float*)d_in[3];
    const float* R0    = (const float*)d_in[4];
    const float* A0    = (const float*)d_in[5];
    const float* Wprep = (const float*)d_in[6];
    const float* bprep = (const float*)d_in[7];
    const float* Wx    = (const float*)d_in[8];
    const float* Wh    = (const float*)d_in[9];
    const float* bl    = (const float*)d_in[10];
    const float* Wr    = (const float*)d_in[11];
    const float* br    = (const float*)d_in[12];
    const float* Ww    = (const float*)d_in[13];
    const float* bw    = (const float*)d_in[14];
    const float* Wo    = (const float*)d_in[15];
    const float* bo    = (const float*)d_in[16];

    float* ws = (float*)d_ws;
    // all offsets in floats, 16B-aligned
    u16*   Wt_lstm = (u16*)(ws + 0);          // 2048*1056 u16 = 1,081,344 f
    u16*   Wt_h    = (u16*)(ws + 1081344);    // 384*512  u16 = 98,304 f
    u16*   Wt_o    = (u16*)(ws + 1179648);    // 512*576  u16 = 147,456 f
    u16*   Abuf    = (u16*)(ws + 1327104);    // 2048*1056 u16 = 1,081,344 f
    u16*   A2      = (u16*)(ws + 2408448);    // 2048*576 u16 = 589,824 f
    float* rout    =        ws + 2998272;     // 2048*70
    float* wout    =        ws + 3141632;     // 2048*198
    // total ~3.55M floats = 14.2 MB

    float* out    = (float*)d_out;
    float* out_y  = out;              // 1048576
    float* out_mt = out + 1048576;    // 33554432
    float* out_rt = out + 34603008;   // 131072
    float* out_wr = out + 34734080;   // 524288
    float* out_ww = out + 35258368;   // 524288

    hipLaunchKernelGGL(k_prep,      dim3(6688), dim3(256), 0, stream,
                       Wx, Wh, Wr, Ww, Wo, x, H0, R0, Wprep, bprep,
                       Wt_lstm, Wt_h, Wt_o, Abuf);
    hipLaunchKernelGGL(k_gemm_lstm, dim3(16,16), dim3(256), 0, stream, Abuf, Wt_lstm, C0, bl, A2);
    hipLaunchKernelGGL(k_gemm_heads, dim3(16,3), dim3(256), 0, stream, A2, Wt_h, br, bw, rout, wout);
    hipLaunchKernelGGL(k_addr,      dim3(2048),  dim3(256), 0, stream, m0, A0, rout, wout, A2,
                       out_mt, out_rt, out_wr, out_ww);
    hipLaunchKernelGGL(k_gemm_out,  dim3(16,4),  dim3(256), 0, stream, A2, Wt_o, bo, out_y);
}

// Round 6
// 374.185 us; speedup vs baseline: 1.1291x; 1.1291x over previous
//
#include <hip/hip_runtime.h>

// NTM cell forward. f32 in/out, bf16 MFMA for all large GEMMs (tolerance is bf16-grade).
// B=2048 N=256 M=64 U=512 IN=10 SHIFT=1 CLIP=20
// Outputs flat (f32): y_t[B*512] | m_t[B*256*64] | R_t[B*64] | w_read[B*256] | w_write[B*256]
// R6: k_addr rewritten at 512 threads/block: 8 float4 (32 VGPR) retained m0 per thread,
//     per-head softmax split (threads 0-255 = head0, 256-511 = head1). GEMM/prep = r4 state.

using u16   = unsigned short;
using bfrag = __attribute__((ext_vector_type(8))) short;   // 8 bf16 (4 VGPRs)
using f4    = __attribute__((ext_vector_type(4))) float;   // MFMA accumulator

__device__ __forceinline__ float bf2f(u16 s){ union{float f;unsigned u;}v; v.u=((unsigned)s)<<16; return v.f; }
__device__ __forceinline__ u16 f2bf(float f){ union{float f;unsigned u;}v; v.f=f; unsigned r=v.u+0x7fffu+((v.u>>16)&1u); return (u16)(r>>16); }
__device__ __forceinline__ float sigm(float x){ return 1.f/(1.f+expf(-x)); }
__device__ __forceinline__ float softplus_(float x){ return fmaxf(x,0.f)+log1pf(expf(-fabsf(x))); }

// async global->LDS, 16B per lane; lptr must be wave-uniform (HW adds lane*16)
__device__ __forceinline__ void gld16(const u16* g, u16* l){
    __builtin_amdgcn_global_load_lds((const __attribute__((address_space(1))) unsigned*)g,
                                     (__attribute__((address_space(3))) unsigned*)l, 16, 0, 0);
}

// ======================= fused prep: weight transposes + A-build, one launch =======================
// role 0 (blocks [0,2112)):    Wt_lstm  [n'][k] bf16, lda=1056, GATE-INTERLEAVED rows:
//                              orig col n = gate*512+u  ->  n' = (u>>4)*64 + gate*16 + (u&15)
// role 1 (blocks [2112,2304)): Wt_h [n][k] bf16 (n<384 pad), ldb=512
// role 2 (blocks [2304,2592)): Wt_o [n][k] bf16, ldb=576
// role 3 (blocks [2592,6688)): Abuf = [x | R0@Wprep+bprep | H0 | 0], bf16, lda=1056
__global__ __launch_bounds__(256) void k_prep(const float* __restrict__ Wx, const float* __restrict__ Wh,
                                              const float* __restrict__ Wr, const float* __restrict__ Ww,
                                              const float* __restrict__ Wo,
                                              const float* __restrict__ x, const float* __restrict__ H0,
                                              const float* __restrict__ R0, const float* __restrict__ Wprep,
                                              const float* __restrict__ bprep,
                                              u16* __restrict__ Wt_lstm, u16* __restrict__ Wt_h,
                                              u16* __restrict__ Wt_o, u16* __restrict__ Abuf){
    __shared__ float t[32][33];
    int bx = blockIdx.x;
    int tx = threadIdx.x & 31, ty = threadIdx.x >> 5;
    if(bx < 2112){                       // ---- Wt_lstm transpose + gate interleave ----
        int n0 = (bx & 63)*32, k0 = (bx >> 6)*32;
        #pragma unroll
        for(int r=0;r<4;r++){
            int k = k0 + ty*4 + r, n = n0 + tx;
            float v;
            if(k < 522)       v = Wx[k*2048 + n];
            else if(k < 1034) v = Wh[(k-522)*2048 + n];
            else              v = 0.f;
            t[ty*4+r][tx] = v;
        }
        __syncthreads();
        #pragma unroll
        for(int r=0;r<4;r++){
            int n = n0 + ty*4 + r, k = k0 + tx;
            int u = n & 511, gate = n >> 9;
            int np = ((u>>4)<<6) + (gate<<4) + (u&15);   // gate-interleaved row
            Wt_lstm[np*1056 + k] = f2bf(t[tx][ty*4+r]);
        }
    } else if(bx < 2304){                // ---- Wt_h transpose ----
        int idx = bx - 2112;
        int n0 = (idx % 12)*32, k0 = (idx / 12)*32;
        #pragma unroll
        for(int r=0;r<4;r++){
            int k = k0 + ty*4 + r, n = n0 + tx;
            float v;
            if(n < 70)        v = Wr[k*70 + n];
            else if(n < 268)  v = Ww[k*198 + (n-70)];
            else              v = 0.f;
            t[ty*4+r][tx] = v;
        }
        __syncthreads();
        #pragma unroll
        for(int r=0;r<4;r++){
            int n = n0 + ty*4 + r, k = k0 + tx;
            Wt_h[n*512 + k] = f2bf(t[tx][ty*4+r]);
        }
    } else if(bx < 2592){                // ---- Wt_o transpose ----
        int idx = bx - 2304;
        int n0 = (idx % 16)*32, k0 = (idx / 16)*32;
        #pragma unroll
        for(int r=0;r<4;r++){
            int k = k0 + ty*4 + r, n = n0 + tx;
            t[ty*4+r][tx] = Wo[k*512 + n];
        }
        __syncthreads();
        #pragma unroll
        for(int r=0;r<4;r++){
            int n = n0 + ty*4 + r, k = k0 + tx;
            Wt_o[n*576 + k] = f2bf(t[tx][ty*4+r]);
        }
    } else {                             // ---- A-build ----
        int flat = (bx - 2592)*256 + threadIdx.x;   // B*512
        int b = flat >> 9, u = flat & 511;
        u16* Ab = Abuf + (size_t)b*1056;
        float acc = bprep[u];
        const float* r = R0 + b*64;
        #pragma unroll 8
        for(int m=0;m<64;m++) acc += r[m] * Wprep[m*512+u];
        Ab[10+u] = f2bf(acc);
        Ab[522+u] = f2bf(H0[b*512+u]);
        if(u<10) Ab[u] = f2bf(x[b*10+u]);
        if(u<22) Ab[1034+u] = 0;                   // zero K-pad 1034..1055
    }
}

// ======================= MFMA GEMM core: 128x128 C tile, BK=32 =======================
__device__ __forceinline__ void gemm128(const u16* __restrict__ A, int lda,
                                        const u16* __restrict__ Bt, int ldb,
                                        int bm, int bn, int kiters,
                                        u16* Al, u16* Bl, f4 acc[4][4]){
    int tid = threadIdx.x, w = tid>>6, lane = tid&63, quad = lane>>4, l16 = lane&15;
    int wr = w>>1, wc = w&1;
    f4 z4 = {0.f,0.f,0.f,0.f};
    #pragma unroll
    for(int i=0;i<4;i++)
        #pragma unroll
        for(int j=0;j<4;j++) acc[i][j] = z4;
    int rA0 = tid>>2, kc = tid&3;
    int rA1 = rA0 + 64;
    const u16* ga0 = A  + (size_t)(bm+rA0)*lda + kc*8;
    const u16* ga1 = A  + (size_t)(bm+rA1)*lda + kc*8;
    const u16* gb0 = Bt + (size_t)(bn+rA0)*ldb + kc*8;
    const u16* gb1 = Bt + (size_t)(bn+rA1)*ldb + kc*8;
    u16* lA0 = Al + (w*64)*8;
    u16* lA1 = Al + (256 + w*64)*8;
    u16* lB0 = Bl + (w*64)*8;
    u16* lB1 = Bl + (256 + w*64)*8;
    for(int kt=0; kt<kiters; kt++){
        __syncthreads();
        gld16(ga0, lA0); gld16(ga1, lA1);
        gld16(gb0, lB0); gld16(gb1, lB1);
        ga0 += 32; ga1 += 32; gb0 += 32; gb1 += 32;
        __syncthreads();
        bfrag af[4], bf[4];
        #pragma unroll
        for(int i=0;i<4;i++) af[i] = *(const bfrag*)&Al[(wr*64 + i*16 + l16)*32 + quad*8];
        #pragma unroll
        for(int j=0;j<4;j++) bf[j] = *(const bfrag*)&Bl[(wc*64 + j*16 + l16)*32 + quad*8];
        #pragma unroll
        for(int i=0;i<4;i++)
            #pragma unroll
            for(int j=0;j<4;j++)
                acc[i][j] = __builtin_amdgcn_mfma_f32_16x16x32_bf16(af[i], bf[j], acc[i][j], 0, 0, 0);
    }
}
// C/D mapping (m89-verified): col = lane&15, row = quad*4 + reg.

// ------------- GEMM 1 + fused LSTM gates: A@Wt_lstm^T with gate-interleaved cols -------------
__global__ __launch_bounds__(256) void k_gemm_lstm(const u16* __restrict__ A, const u16* __restrict__ Wt,
                                                   const float* __restrict__ C0, const float* __restrict__ bl,
                                                   u16* __restrict__ A2){
    __shared__ u16 Al[128*32], Bl[128*32];
    f4 acc[4][4];
    int bm = blockIdx.x*128, bn = blockIdx.y*128;
    gemm128(A, 1056, Wt, 1056, bm, bn, 33, Al, Bl, acc);
    int lane = threadIdx.x&63, quad = lane>>4, l16 = lane&15, w = threadIdx.x>>6;
    int wr = w>>1, wc = w&1;
    int u = (((bn + wc*64)>>6)<<4) + l16;
    float bi = bl[u], bff = bl[512+u], bg = bl[1024+u], bo_ = bl[1536+u];
    #pragma unroll
    for(int i=0;i<4;i++){
        #pragma unroll
        for(int r=0;r<4;r++){
            int b = bm + wr*64 + i*16 + quad*4 + r;
            float zi = acc[i][0][r] + bi;
            float zf = acc[i][1][r] + bff;
            float zg = acc[i][2][r] + bg;
            float zo = acc[i][3][r] + bo_;
            float c  = sigm(zf)*C0[b*512+u] + sigm(zi)*tanhf(zg);
            float hv = sigm(zo)*tanhf(c);
            hv = fminf(fmaxf(hv,-20.f),20.f);
            A2[(size_t)b*576 + u] = f2bf(hv);
        }
    }
}

// ------------- GEMM 2: [rout|wout] = h @ Wt_h^T  (2048 x 268(pad 384), K=512) -------------
__global__ __launch_bounds__(256) void k_gemm_heads(const u16* __restrict__ A2, const u16* __restrict__ Wt,
                                                    const float* __restrict__ br, const float* __restrict__ bw,
                                                    float* __restrict__ rout, float* __restrict__ wout){
    __shared__ u16 Al[128*32], Bl[128*32];
    f4 acc[4][4];
    int bm = blockIdx.x*128, bn = blockIdx.y*128;
    gemm128(A2, 576, Wt, 512, bm, bn, 16, Al, Bl, acc);
    int lane = threadIdx.x&63, quad = lane>>4, l16 = lane&15, w = threadIdx.x>>6;
    int wr = w>>1, wc = w&1;
    #pragma unroll
    for(int i=0;i<4;i++){
        #pragma unroll
        for(int j=0;j<4;j++){
            int col = bn + wc*64 + j*16 + l16;
            if(col >= 268) continue;
            #pragma unroll
            for(int r=0;r<4;r++){
                int row = bm + wr*64 + i*16 + quad*4 + r;
                float v = acc[i][j][r];
                if(col < 70) rout[(size_t)row*70 + col]        = v + br[col];
                else         wout[(size_t)row*198 + (col-70)]  = v + bw[col-70];
            }
        }
    }
}

// ------------- GEMM 3: y = clip([h|R_t] @ Wt_o^T + bo)  (2048 x 512, K=576) -------------
__global__ __launch_bounds__(256) void k_gemm_out(const u16* __restrict__ A2, const u16* __restrict__ Wt,
                                                  const float* __restrict__ bo, float* __restrict__ y){
    __shared__ u16 Al[128*32], Bl[128*32];
    f4 acc[4][4];
    int bm = blockIdx.x*128, bn = blockIdx.y*128;
    gemm128(A2, 576, Wt, 576, bm, bn, 18, Al, Bl, acc);
    int lane = threadIdx.x&63, quad = lane>>4, l16 = lane&15, w = threadIdx.x>>6;
    int wr = w>>1, wc = w&1;
    #pragma unroll
    for(int i=0;i<4;i++){
        #pragma unroll
        for(int j=0;j<4;j++){
            int col = bn + wc*64 + j*16 + l16;
            float bias = bo[col];
            #pragma unroll
            for(int r=0;r<4;r++){
                int row = bm + wr*64 + i*16 + quad*4 + r;
                float v = acc[i][j][r] + bias;
                v = fminf(fmaxf(v,-20.f),20.f);
                y[(size_t)row*512 + col] = v;
            }
        }
    }
}

// ------------- K4: per-b fused addressing (both heads) + R_t + m_t, 512 threads -------------
// Thread t owns m0[b][i*32+g][mc..mc+3], i=0..7, where g=t>>4, mc=(t&15)*4 -> 8 float4
// (32 VGPR) retained across all phases. Softmax chain split by head: threads 0-255 do
// head 0 rows, 256-511 head 1 rows (halves the per-thread transcendental chain).
__global__ __launch_bounds__(512, 2) void k_addr(const float* __restrict__ m0, const float* __restrict__ A0,
                                              const float* __restrict__ rout, const float* __restrict__ wout,
                                              u16* __restrict__ A2,
                                              float* __restrict__ out_mt, float* __restrict__ out_rt,
                                              float* __restrict__ out_wr, float* __restrict__ out_ww){
    __shared__ __align__(16) float kk_s[2][64];   // tanh(k), both heads
    __shared__ float knorm_s[2];
    __shared__ float sc[2][6];                    // beta-sp, g, s0,s1,s2, gamma-sp
    __shared__ float ipbuf[3][272];               // padded: slot(n) = n + (n>>4)
    __shared__ float wgrr[512];                   // wg[h*256 + r]
    __shared__ float wsel[2][256];
    __shared__ __align__(16) float dv[64], avv[64];
    __shared__ float wpart[8][3];                 // per-wave partials: max, sum, wsum
    __shared__ __align__(16) float rred[32][64];  // R_t partials (8 KB)
    int tid = threadIdx.x, b = blockIdx.x;
    int lane = tid & 63, w = tid >> 6;            // w 0..7
    int g = tid >> 4, c = tid & 15, mc = c*4;     // g 0..31

    int hh = tid >> 8, rr = tid & 255;            // this thread's (head,row) for softmax
    float ar = A0[hh*524288 + b*256 + rr];        // a_tm1 for own (head,row)

    // ---- m0 -> 8 float4 registers (32 VGPR), single HBM read, coalesced ----
    float4 v[8];
    const float* mb = m0 + (size_t)b*16384;
    #pragma unroll
    for(int i=0;i<8;i++) v[i] = *(const float4*)(mb + i*2048 + tid*4);
    // v[i] = m0[b][i*32+g][mc..mc+3]

    // ---- head scalars, split across waves ----
    if(tid < 128){
        int h2 = tid >> 6, m = lane;
        float kv = tanhf(h2 ? wout[b*198 + m] : rout[b*70 + m]);
        kk_s[h2][m] = kv;
        float s2 = kv*kv;
        #pragma unroll
        for(int o=32;o>0;o>>=1) s2 += __shfl_xor(s2, o, 64);
        if(m == 0) knorm_s[h2] = sqrtf(s2);
    } else if(tid < 192){
        int h2 = tid - 128;
        if(h2 < 2){
            const float* hd = h2 ? (wout + b*198) : (rout + b*70);
            sc[h2][0] = softplus_(hd[64]);
            sc[h2][1] = sigm(hd[65]);
            float e0=hd[66], e1=hd[67], e2=hd[68];
            float mx = fmaxf(e0, fmaxf(e1, e2));
            float x0=expf(e0-mx), x1=expf(e1-mx), x2=expf(e2-mx);
            float ssum = x0+x1+x2;
            sc[h2][2]=x0/ssum; sc[h2][3]=x1/ssum; sc[h2][4]=x2/ssum;
            sc[h2][5] = softplus_(hd[69]);
        }
    } else if(tid < 256){
        int m = tid - 192;
        dv[m]  = sigm(wout[b*198 + 70 + m]);
    } else if(tid < 320){
        int m = tid - 256;
        avv[m] = tanhf(wout[b*198 + 134 + m]);
    }
    __syncthreads();   // (1) kk_s/sc/dv/avv visible

    // ---- dual-head ip + ssq per row, 16-lane-group butterfly, redistribute ----
    {
        float4 ka = *(const float4*)&kk_s[0][mc];
        float4 kb = *(const float4*)&kk_s[1][mc];
        #pragma unroll
        for(int i=0;i<8;i++){
            float4 t = v[i];
            float p0 = t.x*ka.x + t.y*ka.y + t.z*ka.z + t.w*ka.w;
            float p1 = t.x*kb.x + t.y*kb.y + t.z*kb.z + t.w*kb.w;
            float ps = t.x*t.x + t.y*t.y + t.z*t.z + t.w*t.w;
            #pragma unroll
            for(int o=1;o<16;o<<=1){
                p0 += __shfl_xor(p0, o);
                p1 += __shfl_xor(p1, o);
                ps += __shfl_xor(ps, o);
            }
            if(c == i){                         // lanes c==i (i<8) keep row i*32+g
                int n = i*32 + g;
                int slot = n + (n>>4);
                ipbuf[0][slot] = p0;
                ipbuf[1][slot] = p1;
                ipbuf[2][slot] = ps;
            }
        }
    }
    __syncthreads();   // (2) ipbuf visible

    // ---- per-head softmax chain (thread handles row rr of head hh) ----
    int rslot = rr + (rr>>4);
    float ip  = ipbuf[hh][rslot];
    float ssq = ipbuf[2][rslot];
    float mn = sqrtf(ssq);
    float K = ip / (knorm_s[hh]*mn + 1e-8f);
    float e = sc[hh][0]*K;

    int wb = hh*4;   // this head's wave range: waves wb..wb+3
    float mx = e;
    #pragma unroll
    for(int o=32;o>0;o>>=1) mx = fmaxf(mx, __shfl_xor(mx,o,64));
    if(lane == 0) wpart[w][0] = mx;
    __syncthreads();   // (3)
    mx = fmaxf(fmaxf(wpart[wb][0],wpart[wb+1][0]), fmaxf(wpart[wb+2][0],wpart[wb+3][0]));
    float p = expf(e-mx);
    float s = p;
    #pragma unroll
    for(int o=32;o>0;o>>=1) s += __shfl_xor(s,o,64);
    if(lane == 0) wpart[w][1] = s;
    __syncthreads();   // (4)
    s = wpart[wb][1]+wpart[wb+1][1]+wpart[wb+2][1]+wpart[wb+3][1];
    float wc = p/s;

    float gg = sc[hh][1];
    float wg = gg*wc + (1.f-gg)*ar;
    wgrr[tid] = wg;
    __syncthreads();   // (5)
    int base = hh<<8;
    float conv = sc[hh][2]*wg + sc[hh][3]*wgrr[base + ((rr+255)&255)]
                              + sc[hh][4]*wgrr[base + ((rr+1)&255)];
    conv = fmaxf(conv, 1e-35f);
    float wsh = expf(sc[hh][5]*logf(conv));
    float t0 = wsh;
    #pragma unroll
    for(int o=32;o>0;o>>=1) t0 += __shfl_xor(t0,o,64);
    if(lane == 0) wpart[w][2] = t0;
    __syncthreads();   // (6)
    t0 = wpart[wb][2]+wpart[wb+1][2]+wpart[wb+2][2]+wpart[wb+3][2];
    float wfin = wsh/t0;
    wsel[hh][rr] = wfin;
    (hh ? out_ww : out_wr)[b*256 + rr] = wfin;
    __syncthreads();   // (7) wsel visible

    // ---- m_t from retained registers + fused R_t partials ----
    float r0=0.f, r1=0.f, r2=0.f, r3=0.f;
    {
        float d0=dv[mc], d1=dv[mc+1], d2=dv[mc+2], d3=dv[mc+3];
        float A0v=avv[mc], A1v=avv[mc+1], A2v=avv[mc+2], A3v=avv[mc+3];
        float* outb = out_mt + (size_t)b*16384;
        #pragma unroll
        for(int i=0;i<8;i++){
            int n = i*32 + g;
            float wwv = wsel[1][n], wrv = wsel[0][n];   // 16-lane broadcast
            float4 t = v[i];
            float4 o;
            o.x = t.x*(1.f - wwv*d0) + wwv*A0v;
            o.y = t.y*(1.f - wwv*d1) + wwv*A1v;
            o.z = t.z*(1.f - wwv*d2) + wwv*A2v;
            o.w = t.w*(1.f - wwv*d3) + wwv*A3v;
            *(float4*)(outb + i*2048 + tid*4) = o;
            r0 += wrv*t.x; r1 += wrv*t.y; r2 += wrv*t.z; r3 += wrv*t.w;
        }
    }
    // ---- R_t reduce: 32 g-groups x 64 cols ----
    {
        float4 rv; rv.x=r0; rv.y=r1; rv.z=r2; rv.w=r3;
        *(float4*)&rred[g][mc] = rv;
        __syncthreads();   // (8)
        if(tid < 64){
            float rt = 0.f;
            #pragma unroll
            for(int g2=0; g2<32; g2++) rt += rred[g2][tid];
            out_rt[b*64 + tid] = rt;
            A2[(size_t)b*576 + 512 + tid] = f2bf(rt);   // feed out-GEMM
        }
    }
}

extern "C" void kernel_launch(void* const* d_in, const int* in_sizes, int n_in,
                              void* d_out, int out_size, void* d_ws, size_t ws_size,
                              hipStream_t stream) {
    const float* x     = (const float*)d_in[0];
    const float* H0    = (const float*)d_in[1];
    const float* C0    = (const float*)d_in[2];
    const float* m0    = (const float*)d_in[3];
    const float* R0    = (const float*)d_in[4];
    const float* A0    = (const float*)d_in[5];
    const float* Wprep = (const float*)d_in[6];
    const float* bprep = (const float*)d_in[7];
    const float* Wx    = (const float*)d_in[8];
    const float* Wh    = (const float*)d_in[9];
    const float* bl    = (const float*)d_in[10];
    const float* Wr    = (const float*)d_in[11];
    const float* br    = (const float*)d_in[12];
    const float* Ww    = (const float*)d_in[13];
    const float* bw    = (const float*)d_in[14];
    const float* Wo    = (const float*)d_in[15];
    const float* bo    = (const float*)d_in[16];

    float* ws = (float*)d_ws;
    // all offsets in floats, 16B-aligned
    u16*   Wt_lstm = (u16*)(ws + 0);          // 2048*1056 u16 = 1,081,344 f
    u16*   Wt_h    = (u16*)(ws + 1081344);    // 384*512  u16 = 98,304 f
    u16*   Wt_o    = (u16*)(ws + 1179648);    // 512*576  u16 = 147,456 f
    u16*   Abuf    = (u16*)(ws + 1327104);    // 2048*1056 u16 = 1,081,344 f
    u16*   A2      = (u16*)(ws + 2408448);    // 2048*576 u16 = 589,824 f
    float* rout    =        ws + 2998272;     // 2048*70
    float* wout    =        ws + 3141632;     // 2048*198
    // total ~3.55M floats = 14.2 MB

    float* out    = (float*)d_out;
    float* out_y  = out;              // 1048576
    float* out_mt = out + 1048576;    // 33554432
    float* out_rt = out + 34603008;   // 131072
    float* out_wr = out + 34734080;   // 524288
    float* out_ww = out + 35258368;   // 524288

    hipLaunchKernelGGL(k_prep,      dim3(6688), dim3(256), 0, stream,
                       Wx, Wh, Wr, Ww, Wo, x, H0, R0, Wprep, bprep,
                       Wt_lstm, Wt_h, Wt_o, Abuf);
    hipLaunchKernelGGL(k_gemm_lstm, dim3(16,16), dim3(256), 0, stream, Abuf, Wt_lstm, C0, bl, A2);
    hipLaunchKernelGGL(k_gemm_heads, dim3(16,3), dim3(256), 0, stream, A2, Wt_h, br, bw, rout, wout);
    hipLaunchKernelGGL(k_addr,      dim3(2048),  dim3(512), 0, stream, m0, A0, rout, wout, A2,
                       out_mt, out_rt, out_wr, out_ww);
    hipLaunchKernelGGL(k_gemm_out,  dim3(16,4),  dim3(256), 0, stream, A2, Wt_o, bo, out_y);
}